// Round 22
// baseline (868.449 us; speedup 1.0000x reference)
//
#include <hip/hip_runtime.h>
#include <hip/hip_bf16.h>
#include <math.h>

#define NODE 90
#define HID 256
#define NB 512
#define NN (NB * 90)
#define EDGES (NB * 2700)
#define XLD 96

typedef __attribute__((ext_vector_type(8))) short bf16x8;
typedef __attribute__((ext_vector_type(4))) float f32x4;

__device__ __forceinline__ float tanh_safe(float s) {
    s = fminf(fmaxf(s, -15.f), 15.f);
    float t = __expf(2.f * s);
    return (t - 1.f) / (t + 1.f);
}
__device__ __forceinline__ unsigned short f2b(float x) {
    unsigned u = __float_as_uint(x);
    return (unsigned short)((u + 0x7FFFu + ((u >> 16) & 1u)) >> 16);
}
__device__ __forceinline__ float b2f(unsigned short h) {
    return __uint_as_float(((unsigned)h) << 16);
}

// ---------------------------------------------------------------------------
__device__ float g_adjS[(size_t)NB * NODE * NODE];
__device__ float g_adjF[(size_t)NB * NODE * NODE];
__device__ float g_T[(size_t)2 * NN * HID];

__device__ unsigned short g_hshi[(size_t)NN * HID], g_hslo[(size_t)NN * HID];
__device__ unsigned short g_hfhi[(size_t)NN * HID], g_hflo[(size_t)NN * HID];
__device__ unsigned short g_cshi[(size_t)NN * HID], g_cslo[(size_t)NN * HID];
__device__ unsigned short g_cfhi[(size_t)NN * HID], g_cflo[(size_t)NN * HID];
__device__ unsigned short g_w0thi[256 * XLD], g_w0tlo[256 * XLD];
__device__ unsigned short g_wathi[256 * 256], g_watlo[256 * 256];
__device__ unsigned short g_w1thi[256 * 512], g_w1tlo[256 * 512];

__device__ __forceinline__ float* adjPtr(int w) { return w ? g_adjF : g_adjS; }
__device__ __forceinline__ unsigned short* selhi(int w) {
    switch (w) {
        case 0: return g_hshi;
        case 1: return g_hfhi;
        case 2: return g_cshi;
        default: return g_cfhi;
    }
}
__device__ __forceinline__ unsigned short* sello(int w) {
    switch (w) {
        case 0: return g_hslo;
        case 1: return g_hflo;
        case 2: return g_cslo;
        default: return g_cflo;
    }
}
__device__ __forceinline__ unsigned short* wthi(int w) {
    switch (w) { case 0: return g_w0thi; case 1: return g_wathi; default: return g_w1thi; }
}
__device__ __forceinline__ unsigned short* wtlo(int w) {
    switch (w) { case 0: return g_w0tlo; case 1: return g_watlo; default: return g_w1tlo; }
}

// ---------------------------------------------------------------------------
// Prep: blocks [0,1024) adjacency (dtype-detecting); [1024,1132) weight planes.
// ---------------------------------------------------------------------------
__global__ __launch_bounds__(256) void k_prep(const void* __restrict__ eS,
                                              const void* __restrict__ eF,
                                              const float* __restrict__ W0,
                                              const float* __restrict__ Wa,
                                              const float* __restrict__ W1) {
    int tid = threadIdx.x;
    if (blockIdx.x < 1024) {
        __shared__ float cnt[NODE][NODE + 1];
        __shared__ float dinv[NODE];
        __shared__ int s_e64;
        int side = blockIdx.x >> 9;
        int b = blockIdx.x & 511;
        const void* edges = side ? eF : eS;
        const int* p32 = (const int*)edges;
        if (tid == 0) s_e64 = 1;
        for (int i = tid; i < NODE * (NODE + 1); i += 256) (&cnt[0][0])[i] = 0.f;
        __syncthreads();
        for (int i = tid; i < 1024; i += 256)
            if (p32[2 * i + 1] != 0) s_e64 = 0;
        __syncthreads();
        int e64 = s_e64;
        const long long* p64 = (const long long*)edges;
        for (int i = tid; i < 2700; i += 256) {
            int idx = b * 2700 + i;
            long long s, d;
            if (e64) { s = p64[idx]; d = p64[EDGES + idx]; }
            else     { s = p32[idx]; d = p32[EDGES + idx]; }
            int sl = (int)s - b * NODE, dl = (int)d - b * NODE;
            if (sl >= 0 && sl < NODE && dl >= 0 && dl < NODE)
                atomicAdd(&cnt[dl][sl], 1.0f);
        }
        __syncthreads();
        if (tid < NODE) {
            float s = 0.f;
            for (int k = 0; k < NODE; k++) s += cnt[tid][k];
            dinv[tid] = (s > 0.f) ? rsqrtf(s) : 0.f;
        }
        __syncthreads();
        float* adj = adjPtr(side) + (size_t)b * NODE * NODE;
        for (int i = tid; i < NODE * NODE; i += 256) {
            int d = i / NODE, s = i - d * NODE;
            adj[i] = cnt[d][s] * dinv[d] * dinv[s];
        }
    } else {
        int gid = blockIdx.x - 1024;
        const float* W;
        int K, Kpad, which, t;
        if (gid < 12)      { W = W0; K = NODE; Kpad = XLD; which = 0; t = gid * 256 + tid; }
        else if (gid < 44) { W = Wa; K = 256;  Kpad = 256; which = 1; t = (gid - 12) * 256 + tid; }
        else               { W = W1; K = 512;  Kpad = 512; which = 2; t = (gid - 44) * 256 + tid; }
        int c = t / (Kpad / 8), o = t - c * (Kpad / 8);
        unsigned short h8[8], l8[8];
#pragma unroll
        for (int j = 0; j < 8; j++) {
            int k = 8 * o + j;
            float x = (k < K) ? W[(size_t)k * 256 + c] : 0.f;
            unsigned short h = f2b(x);
            h8[j] = h;
            l8[j] = f2b(x - b2f(h));
        }
        *(uint4*)&wthi(which)[(size_t)c * Kpad + 8 * o] = *(uint4*)h8;
        *(uint4*)&wtlo(which)[(size_t)c * Kpad + 8 * o] = *(uint4*)l8;
    }
}

// ---------------------------------------------------------------------------
// Two-sided MFMA bf16x2-split GEMM, full-width blocks (64 rows x 256 cols).
// xsel<=3: bf16 plane inputs; xsel==6: fp32 external (xpA/xpB, ld 90, Kpad 96).
// ---------------------------------------------------------------------------
#define GK 32
#define ASTR 40
__global__ __launch_bounds__(256) void k_gemm_mfma(int xsA, int x2sA, int xsB, int x2sB,
                                                   int kld, int K, int wsel, int wld,
                                                   int nSide,
                                                   const float* __restrict__ xpA,
                                                   const float* __restrict__ xpB) {
    __shared__ unsigned short Ah[64][ASTR], Al[64][ASTR];
    __shared__ unsigned short Bh[256][ASTR], Bl[256][ASTR];
    int tid = threadIdx.x;
    int id = blockIdx.x;
    int side = (id >= nSide);
    int bm = side ? id - nSide : id;
    int r0 = bm * 64;
    int tbase = side ? NN : 0;
    int xsel = side ? xsB : xsA;
    int x2sel = side ? x2sB : x2sA;
    const float* xp = side ? xpB : xpA;
    int fx = (xsel >= 6);
    const unsigned short* whi_ = wthi(wsel);
    const unsigned short* wlo_ = wtlo(wsel);

    int w = tid >> 6;
    int l = tid & 63;
    int lr = l & 15;
    int lq = l >> 4;
    int koff = lq * 8;
    int sr = tid >> 2, so = (tid & 3) * 8;

    f32x4 acc[16];
#pragma unroll
    for (int c = 0; c < 16; c++) acc[c] = (f32x4){0.f, 0.f, 0.f, 0.f};

    int nt = K / GK;
    for (int t = 0; t < nt; t++) {
        int k0 = t * GK;
        __syncthreads();
        if (fx) {
            float xv[8];
            const float* src = xp + (size_t)(r0 + sr) * 90;
#pragma unroll
            for (int j = 0; j < 8; j++) {
                int k = k0 + so + j;
                xv[j] = (k < 90) ? src[k] : 0.f;
            }
            unsigned short h8[8], l8[8];
#pragma unroll
            for (int j = 0; j < 8; j++) {
                unsigned short h = f2b(xv[j]);
                h8[j] = h;
                l8[j] = f2b(xv[j] - b2f(h));
            }
            *(uint4*)&Ah[sr][so] = *(uint4*)h8;
            *(uint4*)&Al[sr][so] = *(uint4*)l8;
        } else {
            const unsigned short *phi, *plo;
            int xc;
            if (x2sel >= 0 && k0 >= HID) { phi = selhi(x2sel); plo = sello(x2sel); xc = k0 - HID; }
            else                          { phi = selhi(xsel);  plo = sello(xsel);  xc = k0; }
            size_t ga = (size_t)(r0 + sr) * kld + xc + so;
            *(uint4*)&Ah[sr][so] = *(const uint4*)&phi[ga];
            *(uint4*)&Al[sr][so] = *(const uint4*)&plo[ga];
        }
        {
#pragma unroll
            for (int q = 0; q < 4; q++) {
                int i = tid + (q << 8);
                int col = i >> 2, oq = (i & 3) << 3;
                size_t gb = (size_t)col * wld + k0 + oq;
                *(uint4*)&Bh[col][oq] = *(const uint4*)&whi_[gb];
                *(uint4*)&Bl[col][oq] = *(const uint4*)&wlo_[gb];
            }
        }
        __syncthreads();

        bf16x8 ah = *(const bf16x8*)&Ah[16 * w + lr][koff];
        bf16x8 al = *(const bf16x8*)&Al[16 * w + lr][koff];
#pragma unroll
        for (int c = 0; c < 16; c++) {
            bf16x8 bh = *(const bf16x8*)&Bh[16 * c + lr][koff];
            bf16x8 bl = *(const bf16x8*)&Bl[16 * c + lr][koff];
            acc[c] = __builtin_amdgcn_mfma_f32_16x16x32_bf16(ah, bh, acc[c], 0, 0, 0);
            acc[c] = __builtin_amdgcn_mfma_f32_16x16x32_bf16(ah, bl, acc[c], 0, 0, 0);
            acc[c] = __builtin_amdgcn_mfma_f32_16x16x32_bf16(al, bh, acc[c], 0, 0, 0);
        }
    }

#pragma unroll
    for (int c = 0; c < 16; c++) {
#pragma unroll
        for (int qq = 0; qq < 4; qq++) {
            size_t row = (size_t)(tbase + r0 + 16 * w + 4 * lq + qq);
            g_T[row * HID + 16 * c + lr] = acc[c][qq];
        }
    }
}

// ---------------------------------------------------------------------------
// Fused two-stream aggregate; emits h planes + d_out copy.
// ---------------------------------------------------------------------------
__global__ __launch_bounds__(256) void k_agg2(const float* __restrict__ bias,
                                              float* __restrict__ outS,
                                              float* __restrict__ outF) {
    __shared__ float AdjT[NODE][102];
    int tid = threadIdx.x;
    int idx = blockIdx.x;
    int side = idx >> 10;
    int b = (idx & 1023) >> 1;
    int c0 = (idx & 1) * 128;
    const float* Adj = adjPtr(side) + (size_t)b * NODE * NODE;
    const float* Tg = g_T + ((size_t)side * NN + (size_t)b * NODE) * HID;
    float* outp = side ? outF : outS;
    unsigned short* phD = selhi(side);
    unsigned short* plD = sello(side);

    for (int i = tid; i < NODE * NODE; i += 256) {
        int n = i / NODE, k = i - n * NODE;
        AdjT[k][n] = Adj[i];
    }
    for (int i = tid; i < NODE * 12; i += 256) {
        int k = i / 12, n = NODE + (i % 12);
        AdjT[k][n] = 0.f;
    }
    __syncthreads();

    int ti = tid & 15, tj = tid >> 4;
    int rbase = 6 * ti;
    int cc = c0 + 8 * tj;

    float acc[6][8];
#pragma unroll
    for (int i = 0; i < 6; i++)
#pragma unroll
        for (int j = 0; j < 8; j++) acc[i][j] = 0.f;

#pragma unroll 2
    for (int k = 0; k < NODE; k++) {
        float4 t0 = *(const float4*)&Tg[(size_t)k * HID + cc];
        float4 t1 = *(const float4*)&Tg[(size_t)k * HID + cc + 4];
        float bv[8] = {t0.x, t0.y, t0.z, t0.w, t1.x, t1.y, t1.z, t1.w};
        float2 a01 = *(const float2*)&AdjT[k][rbase];
        float2 a23 = *(const float2*)&AdjT[k][rbase + 2];
        float2 a45 = *(const float2*)&AdjT[k][rbase + 4];
        float av[6] = {a01.x, a01.y, a23.x, a23.y, a45.x, a45.y};
#pragma unroll
        for (int i = 0; i < 6; i++)
#pragma unroll
            for (int j = 0; j < 8; j++)
                acc[i][j] = fmaf(av[i], bv[j], acc[i][j]);
    }

    float bb[8];
#pragma unroll
    for (int j = 0; j < 8; j++) bb[j] = bias[cc + j];

#pragma unroll
    for (int i = 0; i < 6; i++) {
        int n = rbase + i;
        if (n < NODE) {
            size_t row = (size_t)(b * NODE + n);
            float v[8];
            unsigned short h8[8], l8[8];
#pragma unroll
            for (int j = 0; j < 8; j++) {
                v[j] = fmaxf(acc[i][j] + bb[j], 0.f);
                unsigned short h = f2b(v[j]);
                h8[j] = h;
                l8[j] = f2b(v[j] - b2f(h));
            }
            *(float4*)&outp[row * 512 + cc] = make_float4(v[0], v[1], v[2], v[3]);
            *(float4*)&outp[row * 512 + cc + 4] = make_float4(v[4], v[5], v[6], v[7]);
            *(uint4*)&phD[row * HID + cc] = *(uint4*)h8;
            *(uint4*)&plD[row * HID + cc] = *(uint4*)l8;
        }
    }
}

// ---------------------------------------------------------------------------
// Fully-fused co-attention per graph:
//   per 32-chunk e0: T2c = Hs @ Wa[:,e0:e0+32] (MFMA, 8 sub-chunks) ->
//   bf16 hi/lo in LDS (identical numerics to old t2-plane path) ->
//   At-acc += T2c @ HFchunk^T (MFMA). Then stats, P in LDS, PV phases.
// LDS carved from one 72.7 KB arena -> 2 blocks/CU.
// ---------------------------------------------------------------------------
__global__ __launch_bounds__(256) void k_coatt(int hfsel, int hssel,
                                               float* __restrict__ outS,
                                               float* __restrict__ outF,
                                               int cssel, int cfsel, int emit) {
    __shared__ __align__(16) char smem[72704];
    unsigned short (*stAH)[ASTR] = (unsigned short(*)[ASTR])(smem);            // 96x40
    unsigned short (*stAL)[ASTR] = (unsigned short(*)[ASTR])(smem + 7680);
    unsigned short (*stBH)[ASTR] = (unsigned short(*)[ASTR])(smem + 15360);    // 32x40
    unsigned short (*stBL)[ASTR] = (unsigned short(*)[ASTR])(smem + 17920);
    unsigned short (*t2cH)[ASTR] = (unsigned short(*)[ASTR])(smem + 20480);    // 96x40
    unsigned short (*t2cL)[ASTR] = (unsigned short(*)[ASTR])(smem + 28160);
    float (*Pm)[92] = (float(*)[92])(smem + 35840);                            // 96x92
    float* rmax_ = (float*)(smem + 71168);
    float* rinv_ = (float*)(smem + 71552);
    float* fn_   = (float*)(smem + 71936);
    float* gm_   = (float*)(smem + 72320);
    float (*Hl)[68] = (float(*)[68])(smem);                                    // aliases stage

    int b = blockIdx.x;
    int tid = threadIdx.x;
    const unsigned short* hsh = selhi(hssel) + (size_t)b * NODE * HID;
    const unsigned short* hsl = sello(hssel) + (size_t)b * NODE * HID;
    const unsigned short* hfh = selhi(hfsel) + (size_t)b * NODE * HID;
    const unsigned short* hfl_ = sello(hfsel) + (size_t)b * NODE * HID;

    int w = tid >> 6, l = tid & 63;
    int lr = l & 15, lq = l >> 4, koff = 8 * lq;
    int wr = w >> 1, wc = w & 1;

    f32x4 acc33[3][3];
#pragma unroll
    for (int i = 0; i < 3; i++)
#pragma unroll
        for (int j = 0; j < 3; j++) acc33[i][j] = (f32x4){0.f, 0.f, 0.f, 0.f};

    const uint4 z4 = make_uint4(0, 0, 0, 0);
    // ---- phase A: for each 32-col chunk e0 of T2/At-contraction ----
    for (int t = 0; t < 8; t++) {
        int e0 = 32 * t;
        // step 1: T2c[96][32] = Hs @ Wa[:, e0:e0+32]  (contraction d = 256)
        f32x4 acc12[3];
#pragma unroll
        for (int i = 0; i < 3; i++) acc12[i] = (f32x4){0.f, 0.f, 0.f, 0.f};
        for (int d0 = 0; d0 < 256; d0 += 32) {
            __syncthreads();
            for (int i = tid; i < 96 * 4; i += 256) {        // Hs chunk
                int r = i >> 2, o = (i & 3) << 3;
                uint4 vh = z4, vl = z4;
                if (r < NODE) {
                    size_t g = (size_t)r * HID + d0 + o;
                    vh = *(const uint4*)&hsh[g];
                    vl = *(const uint4*)&hsl[g];
                }
                *(uint4*)&stAH[r][o] = vh;
                *(uint4*)&stAL[r][o] = vl;
            }
            for (int i = tid; i < 32 * 4; i += 256) {        // WaT rows e0..e0+31
                int r = i >> 2, o = (i & 3) << 3;
                size_t g = (size_t)(e0 + r) * 256 + d0 + o;
                *(uint4*)&stBH[r][o] = *(const uint4*)&g_wathi[g];
                *(uint4*)&stBL[r][o] = *(const uint4*)&g_watlo[g];
            }
            __syncthreads();
#pragma unroll
            for (int i = 0; i < 3; i++) {
                int tt = 3 * w + i, rt = tt >> 1, ct = tt & 1;
                bf16x8 ah = *(const bf16x8*)&stAH[16 * rt + lr][koff];
                bf16x8 al = *(const bf16x8*)&stAL[16 * rt + lr][koff];
                bf16x8 bh = *(const bf16x8*)&stBH[16 * ct + lr][koff];
                bf16x8 bl = *(const bf16x8*)&stBL[16 * ct + lr][koff];
                acc12[i] = __builtin_amdgcn_mfma_f32_16x16x32_bf16(ah, bh, acc12[i], 0, 0, 0);
                acc12[i] = __builtin_amdgcn_mfma_f32_16x16x32_bf16(ah, bl, acc12[i], 0, 0, 0);
                acc12[i] = __builtin_amdgcn_mfma_f32_16x16x32_bf16(al, bh, acc12[i], 0, 0, 0);
            }
        }
        __syncthreads();    // step-1 MFMA reads done; stA reusable
        // step 2: T2c -> bf16 hi/lo LDS (C layout -> [row][k])
#pragma unroll
        for (int i = 0; i < 3; i++) {
            int tt = 3 * w + i, rt = tt >> 1, ct = tt & 1;
#pragma unroll
            for (int qq = 0; qq < 4; qq++) {
                int row = 16 * rt + 4 * lq + qq;
                int col = 16 * ct + lr;
                float v = acc12[i][qq];
                unsigned short h = f2b(v);
                t2cH[row][col] = h;
                t2cL[row][col] = f2b(v - b2f(h));
            }
        }
        // step 3: stage HF chunk into stA
        for (int i = tid; i < 96 * 4; i += 256) {
            int r = i >> 2, o = (i & 3) << 3;
            uint4 vh = z4, vl = z4;
            if (r < NODE) {
                size_t g = (size_t)r * HID + e0 + o;
                vh = *(const uint4*)&hfh[g];
                vl = *(const uint4*)&hfl_[g];
            }
            *(uint4*)&stAH[r][o] = vh;
            *(uint4*)&stAL[r][o] = vl;
        }
        __syncthreads();
        // step 4: At += T2c @ HF^T
        bf16x8 ah[3], al[3], bh[3], bl[3];
#pragma unroll
        for (int i = 0; i < 3; i++) {
            ah[i] = *(const bf16x8*)&t2cH[48 * wr + 16 * i + lr][koff];
            al[i] = *(const bf16x8*)&t2cL[48 * wr + 16 * i + lr][koff];
            bh[i] = *(const bf16x8*)&stAH[48 * wc + 16 * i + lr][koff];
            bl[i] = *(const bf16x8*)&stAL[48 * wc + 16 * i + lr][koff];
        }
#pragma unroll
        for (int i = 0; i < 3; i++)
#pragma unroll
            for (int j = 0; j < 3; j++) {
                acc33[i][j] = __builtin_amdgcn_mfma_f32_16x16x32_bf16(ah[i], bh[j], acc33[i][j], 0, 0, 0);
                acc33[i][j] = __builtin_amdgcn_mfma_f32_16x16x32_bf16(ah[i], bl[j], acc33[i][j], 0, 0, 0);
                acc33[i][j] = __builtin_amdgcn_mfma_f32_16x16x32_bf16(al[i], bh[j], acc33[i][j], 0, 0, 0);
            }
    }
    __syncthreads();

#pragma unroll
    for (int i = 0; i < 3; i++)
#pragma unroll
        for (int j = 0; j < 3; j++)
#pragma unroll
            for (int qq = 0; qq < 4; qq++) {
                int row = 48 * wr + 16 * i + 4 * lq + qq;
                int col = 48 * wc + 16 * j + lr;
                if (col < 92)
                    Pm[row][col] = tanh_safe(acc33[i][j][qq]);
            }
    __syncthreads();

    // ---- softmax stats ----
    if (tid < NODE) {
        int n = tid;
        float mx = -2.f;
        for (int m = 0; m < NODE; m++) mx = fmaxf(mx, Pm[n][m]);
        float s = 0.f;
        for (int m = 0; m < NODE; m++) s += __expf(Pm[n][m] - mx);
        rmax_[n] = mx;
        rinv_[n] = 1.f / s;
        fn_[n] = s * __expf(mx);
    } else if (tid >= 128 && tid < 128 + NODE) {
        int m = tid - 128;
        float mx = -2.f;
        for (int n = 0; n < NODE; n++) mx = fmaxf(mx, Pm[n][m]);
        float s = 0.f;
        for (int n = 0; n < NODE; n++) s += __expf(Pm[n][m] - mx);
        gm_[m] = __expf(-mx) / s;
    }
    __syncthreads();

    for (int i = tid; i < NODE * NODE; i += 256) {
        int n = i / NODE, m = i - n * NODE;
        Pm[n][m] = __expf(Pm[n][m] - rmax_[n]) * rinv_[n];
    }

    int tc = (tid & 15) << 2;
    int rg = tid >> 4;
    unsigned short* csh = selhi(cssel);
    unsigned short* csl = sello(cssel);
    unsigned short* cfh = selhi(cfsel);
    unsigned short* cfl = sello(cfsel);

    // ---- phase B: co_s = P @ HF (4 chunks of 64 cols) ----
    for (int c0 = 0; c0 < HID; c0 += 64) {
        __syncthreads();
        for (int i = tid; i < NODE * 8; i += 256) {
            int r = i >> 3, o = (i & 7) << 3;
            uint4 vh = *(const uint4*)&hfh[(size_t)r * HID + c0 + o];
            uint4 vl = *(const uint4*)&hfl_[(size_t)r * HID + c0 + o];
            const unsigned short* ph = (const unsigned short*)&vh;
            const unsigned short* pl = (const unsigned short*)&vl;
#pragma unroll
            for (int j = 0; j < 8; j++)
                Hl[r][o + j] = b2f(ph[j]) + b2f(pl[j]);
        }
        __syncthreads();

        float acc[6][4];
#pragma unroll
        for (int k = 0; k < 6; k++)
#pragma unroll
            for (int j = 0; j < 4; j++) acc[k][j] = 0.f;

#pragma unroll 2
        for (int m = 0; m < NODE; m++) {
            float4 h = *(const float4*)&Hl[m][tc];
#pragma unroll
            for (int k = 0; k < 6; k++) {
                int n = rg + 16 * k;
                float p = Pm[(n < NODE) ? n : 0][m];
                acc[k][0] = fmaf(p, h.x, acc[k][0]);
                acc[k][1] = fmaf(p, h.y, acc[k][1]);
                acc[k][2] = fmaf(p, h.z, acc[k][2]);
                acc[k][3] = fmaf(p, h.w, acc[k][3]);
            }
        }
#pragma unroll
        for (int k = 0; k < 6; k++) {
            int n = rg + 16 * k;
            if (n < NODE) {
                size_t row = (size_t)(b * NODE + n);
                size_t gc = c0 + tc;
                *(float4*)&outS[row * 512 + gc] =
                    make_float4(acc[k][0], acc[k][1], acc[k][2], acc[k][3]);
                if (emit) {
                    unsigned short h4[4], l4[4];
#pragma unroll
                    for (int j = 0; j < 4; j++) {
                        unsigned short h = f2b(acc[k][j]);
                        h4[j] = h;
                        l4[j] = f2b(acc[k][j] - b2f(h));
                    }
                    *(uint2*)&csh[row * HID + gc] = *(uint2*)h4;
                    *(uint2*)&csl[row * HID + gc] = *(uint2*)l4;
                }
            }
        }
    }

    // ---- phase C: co_f[m] = gm[m] * sum_n (P[n][m]*fn[n]) * HS[n] ----
    for (int c0 = 0; c0 < HID; c0 += 64) {
        __syncthreads();
        for (int i = tid; i < NODE * 8; i += 256) {
            int r = i >> 3, o = (i & 7) << 3;
            uint4 vh = *(const uint4*)&hsh[(size_t)r * HID + c0 + o];
            uint4 vl = *(const uint4*)&hsl[(size_t)r * HID + c0 + o];
            const unsigned short* ph = (const unsigned short*)&vh;
            const unsigned short* pl = (const unsigned short*)&vl;
#pragma unroll
            for (int j = 0; j < 8; j++)
                Hl[r][o + j] = b2f(ph[j]) + b2f(pl[j]);
        }
        __syncthreads();

        float acc[6][4];
#pragma unroll
        for (int k = 0; k < 6; k++)
#pragma unroll
            for (int j = 0; j < 4; j++) acc[k][j] = 0.f;

#pragma unroll 2
        for (int n = 0; n < NODE; n++) {
            float4 h = *(const float4*)&Hl[n][tc];
            float f = fn_[n];
#pragma unroll
            for (int k = 0; k < 6; k++) {
                int m = rg + 16 * k;
                float p = Pm[n][(m < NODE) ? m : 0] * f;
                acc[k][0] = fmaf(p, h.x, acc[k][0]);
                acc[k][1] = fmaf(p, h.y, acc[k][1]);
                acc[k][2] = fmaf(p, h.z, acc[k][2]);
                acc[k][3] = fmaf(p, h.w, acc[k][3]);
            }
        }
#pragma unroll
        for (int k = 0; k < 6; k++) {
            int m = rg + 16 * k;
            if (m < NODE) {
                float g = gm_[m];
                size_t row = (size_t)(b * NODE + m);
                size_t gc = c0 + tc;
                float o4[4] = {acc[k][0] * g, acc[k][1] * g, acc[k][2] * g, acc[k][3] * g};
                *(float4*)&outF[row * 512 + gc] = make_float4(o4[0], o4[1], o4[2], o4[3]);
                if (emit) {
                    unsigned short h4[4], l4[4];
#pragma unroll
                    for (int j = 0; j < 4; j++) {
                        unsigned short h = f2b(o4[j]);
                        h4[j] = h;
                        l4[j] = f2b(o4[j] - b2f(h));
                    }
                    *(uint2*)&cfh[row * HID + gc] = *(uint2*)h4;
                    *(uint2*)&cfl[row * HID + gc] = *(uint2*)l4;
                }
            }
        }
    }
}

// ---------------------------------------------------------------------------
extern "C" void kernel_launch(void* const* d_in, const int* in_sizes, int n_in,
                              void* d_out, int out_size, void* d_ws, size_t ws_size,
                              hipStream_t stream) {
    const float* x_sc = (const float*)d_in[0];
    const void* e_sc = d_in[1];
    const float* x_fc = (const float*)d_in[2];
    const void* e_fc = d_in[3];
    const float* W0 = (const float*)d_in[4];
    const float* b0 = (const float*)d_in[5];
    const float* W1 = (const float*)d_in[6];
    const float* b1 = (const float*)d_in[7];
    const float* Wa = (const float*)d_in[8];

    float* out = (float*)d_out;
    size_t os = (size_t)NN * 512;
    float* x1s = out;
    float* x2s = out + os;
    float* x1f = out + 2 * os;
    float* x2f = out + 3 * os;

    const int NS = NN / 64;          // 720 row-blocks per side

    k_prep<<<1132, 256, 0, stream>>>(e_sc, e_fc, W0, Wa, W1);

    // ---- layer 1 ----
    k_gemm_mfma<<<2 * NS, 256, 0, stream>>>(6, -1, 6, -1, 90, 96, 0, XLD, NS, x_sc, x_fc);
    k_agg2<<<2048, 256, 0, stream>>>(b0, x1s, x1f);

    // ---- co-attention 1 (T2 computed in-kernel) ----
    k_coatt<<<NB, 256, 0, stream>>>(1, 0, x1s + HID, x1f + HID, 2, 3, 1);

    // ---- layer 2 ----
    k_gemm_mfma<<<2 * NS, 256, 0, stream>>>(0, 2, 1, 3, HID, 512, 2, 512, NS, nullptr, nullptr);
    k_agg2<<<2048, 256, 0, stream>>>(b1, x2s, x2f);

    // ---- co-attention 2 ----
    k_coatt<<<NB, 256, 0, stream>>>(1, 0, x2s + HID, x2f + HID, 2, 3, 0);
}

// Round 23
// 769.597 us; speedup vs baseline: 1.1284x; 1.1284x over previous
//
#include <hip/hip_runtime.h>
#include <hip/hip_bf16.h>
#include <math.h>

#define NODE 90
#define HID 256
#define NB 512
#define NN (NB * 90)
#define EDGES (NB * 2700)
#define XLD 96

typedef __attribute__((ext_vector_type(8))) short bf16x8;
typedef __attribute__((ext_vector_type(4))) float f32x4;

__device__ __forceinline__ float tanh_safe(float s) {
    s = fminf(fmaxf(s, -15.f), 15.f);
    float t = __expf(2.f * s);
    return (t - 1.f) / (t + 1.f);
}
__device__ __forceinline__ unsigned short f2b(float x) {
    unsigned u = __float_as_uint(x);
    return (unsigned short)((u + 0x7FFFu + ((u >> 16) & 1u)) >> 16);
}
__device__ __forceinline__ float b2f(unsigned short h) {
    return __uint_as_float(((unsigned)h) << 16);
}

// ---------------------------------------------------------------------------
__device__ float g_adjS[(size_t)NB * NODE * NODE];
__device__ float g_adjF[(size_t)NB * NODE * NODE];
__device__ float g_T[(size_t)2 * NN * HID];

__device__ unsigned short g_hshi[(size_t)NN * HID], g_hslo[(size_t)NN * HID];
__device__ unsigned short g_hfhi[(size_t)NN * HID], g_hflo[(size_t)NN * HID];
__device__ unsigned short g_cshi[(size_t)NN * HID], g_cslo[(size_t)NN * HID];
__device__ unsigned short g_cfhi[(size_t)NN * HID], g_cflo[(size_t)NN * HID];
__device__ unsigned short g_t2hi[(size_t)NN * HID], g_t2lo[(size_t)NN * HID];
__device__ unsigned short g_w0thi[256 * XLD], g_w0tlo[256 * XLD];
__device__ unsigned short g_wathi[256 * 256], g_watlo[256 * 256];
__device__ unsigned short g_w1thi[256 * 512], g_w1tlo[256 * 512];

__device__ __forceinline__ float* adjPtr(int w) { return w ? g_adjF : g_adjS; }
__device__ __forceinline__ unsigned short* selhi(int w) {
    switch (w) {
        case 0: return g_hshi;
        case 1: return g_hfhi;
        case 2: return g_cshi;
        default: return g_cfhi;
    }
}
__device__ __forceinline__ unsigned short* sello(int w) {
    switch (w) {
        case 0: return g_hslo;
        case 1: return g_hflo;
        case 2: return g_cslo;
        default: return g_cflo;
    }
}
__device__ __forceinline__ unsigned short* wthi(int w) {
    switch (w) { case 0: return g_w0thi; case 1: return g_wathi; default: return g_w1thi; }
}
__device__ __forceinline__ unsigned short* wtlo(int w) {
    switch (w) { case 0: return g_w0tlo; case 1: return g_watlo; default: return g_w1tlo; }
}

// ---------------------------------------------------------------------------
// Prep: blocks [0,1024) adjacency (dtype-detecting); [1024,1132) weight planes.
// ---------------------------------------------------------------------------
__global__ __launch_bounds__(256) void k_prep(const void* __restrict__ eS,
                                              const void* __restrict__ eF,
                                              const float* __restrict__ W0,
                                              const float* __restrict__ Wa,
                                              const float* __restrict__ W1) {
    int tid = threadIdx.x;
    if (blockIdx.x < 1024) {
        __shared__ float cnt[NODE][NODE + 1];
        __shared__ float dinv[NODE];
        __shared__ int s_e64;
        int side = blockIdx.x >> 9;
        int b = blockIdx.x & 511;
        const void* edges = side ? eF : eS;
        const int* p32 = (const int*)edges;
        if (tid == 0) s_e64 = 1;
        for (int i = tid; i < NODE * (NODE + 1); i += 256) (&cnt[0][0])[i] = 0.f;
        __syncthreads();
        for (int i = tid; i < 1024; i += 256)
            if (p32[2 * i + 1] != 0) s_e64 = 0;
        __syncthreads();
        int e64 = s_e64;
        const long long* p64 = (const long long*)edges;
        for (int i = tid; i < 2700; i += 256) {
            int idx = b * 2700 + i;
            long long s, d;
            if (e64) { s = p64[idx]; d = p64[EDGES + idx]; }
            else     { s = p32[idx]; d = p32[EDGES + idx]; }
            int sl = (int)s - b * NODE, dl = (int)d - b * NODE;
            if (sl >= 0 && sl < NODE && dl >= 0 && dl < NODE)
                atomicAdd(&cnt[dl][sl], 1.0f);
        }
        __syncthreads();
        if (tid < NODE) {
            float s = 0.f;
            for (int k = 0; k < NODE; k++) s += cnt[tid][k];
            dinv[tid] = (s > 0.f) ? rsqrtf(s) : 0.f;
        }
        __syncthreads();
        float* adj = adjPtr(side) + (size_t)b * NODE * NODE;
        for (int i = tid; i < NODE * NODE; i += 256) {
            int d = i / NODE, s = i - d * NODE;
            adj[i] = cnt[d][s] * dinv[d] * dinv[s];
        }
    } else {
        int gid = blockIdx.x - 1024;
        const float* W;
        int K, Kpad, which, t;
        if (gid < 12)      { W = W0; K = NODE; Kpad = XLD; which = 0; t = gid * 256 + tid; }
        else if (gid < 44) { W = Wa; K = 256;  Kpad = 256; which = 1; t = (gid - 12) * 256 + tid; }
        else               { W = W1; K = 512;  Kpad = 512; which = 2; t = (gid - 44) * 256 + tid; }
        int c = t / (Kpad / 8), o = t - c * (Kpad / 8);
        unsigned short h8[8], l8[8];
#pragma unroll
        for (int j = 0; j < 8; j++) {
            int k = 8 * o + j;
            float x = (k < K) ? W[(size_t)k * 256 + c] : 0.f;
            unsigned short h = f2b(x);
            h8[j] = h;
            l8[j] = f2b(x - b2f(h));
        }
        *(uint4*)&wthi(which)[(size_t)c * Kpad + 8 * o] = *(uint4*)h8;
        *(uint4*)&wtlo(which)[(size_t)c * Kpad + 8 * o] = *(uint4*)l8;
    }
}

// ---------------------------------------------------------------------------
// Two-sided MFMA bf16x2-split GEMM, full-width blocks (64 rows x 256 cols).
// xsel<=3: bf16 plane inputs; xsel==6: fp32 external (xpA/xpB, ld 90, Kpad 96).
// emitT2=1: write hi/lo planes to g_t2* instead of fp32 g_T.
// ---------------------------------------------------------------------------
#define GK 32
#define ASTR 40
__global__ __launch_bounds__(256) void k_gemm_mfma(int xsA, int x2sA, int xsB, int x2sB,
                                                   int kld, int K, int wsel, int wld,
                                                   int emitT2, int nSide,
                                                   const float* __restrict__ xpA,
                                                   const float* __restrict__ xpB) {
    __shared__ unsigned short Ah[64][ASTR], Al[64][ASTR];
    __shared__ unsigned short Bh[256][ASTR], Bl[256][ASTR];
    int tid = threadIdx.x;
    int id = blockIdx.x;
    int side = (id >= nSide);
    int bm = side ? id - nSide : id;
    int r0 = bm * 64;
    int tbase = side ? NN : 0;
    int xsel = side ? xsB : xsA;
    int x2sel = side ? x2sB : x2sA;
    const float* xp = side ? xpB : xpA;
    int fx = (xsel >= 6);
    const unsigned short* whi_ = wthi(wsel);
    const unsigned short* wlo_ = wtlo(wsel);

    int w = tid >> 6;
    int l = tid & 63;
    int lr = l & 15;
    int lq = l >> 4;
    int koff = lq * 8;
    int sr = tid >> 2, so = (tid & 3) * 8;

    f32x4 acc[16];
#pragma unroll
    for (int c = 0; c < 16; c++) acc[c] = (f32x4){0.f, 0.f, 0.f, 0.f};

    int nt = K / GK;
    for (int t = 0; t < nt; t++) {
        int k0 = t * GK;
        __syncthreads();
        if (fx) {
            float xv[8];
            const float* src = xp + (size_t)(r0 + sr) * 90;
#pragma unroll
            for (int j = 0; j < 8; j++) {
                int k = k0 + so + j;
                xv[j] = (k < 90) ? src[k] : 0.f;
            }
            unsigned short h8[8], l8[8];
#pragma unroll
            for (int j = 0; j < 8; j++) {
                unsigned short h = f2b(xv[j]);
                h8[j] = h;
                l8[j] = f2b(xv[j] - b2f(h));
            }
            *(uint4*)&Ah[sr][so] = *(uint4*)h8;
            *(uint4*)&Al[sr][so] = *(uint4*)l8;
        } else {
            const unsigned short *phi, *plo;
            int xc;
            if (x2sel >= 0 && k0 >= HID) { phi = selhi(x2sel); plo = sello(x2sel); xc = k0 - HID; }
            else                          { phi = selhi(xsel);  plo = sello(xsel);  xc = k0; }
            size_t ga = (size_t)(r0 + sr) * kld + xc + so;
            *(uint4*)&Ah[sr][so] = *(const uint4*)&phi[ga];
            *(uint4*)&Al[sr][so] = *(const uint4*)&plo[ga];
        }
        {
#pragma unroll
            for (int q = 0; q < 4; q++) {
                int i = tid + (q << 8);
                int col = i >> 2, oq = (i & 3) << 3;
                size_t gb = (size_t)col * wld + k0 + oq;
                *(uint4*)&Bh[col][oq] = *(const uint4*)&whi_[gb];
                *(uint4*)&Bl[col][oq] = *(const uint4*)&wlo_[gb];
            }
        }
        __syncthreads();

        bf16x8 ah = *(const bf16x8*)&Ah[16 * w + lr][koff];
        bf16x8 al = *(const bf16x8*)&Al[16 * w + lr][koff];
#pragma unroll
        for (int c = 0; c < 16; c++) {
            bf16x8 bh = *(const bf16x8*)&Bh[16 * c + lr][koff];
            bf16x8 bl = *(const bf16x8*)&Bl[16 * c + lr][koff];
            acc[c] = __builtin_amdgcn_mfma_f32_16x16x32_bf16(ah, bh, acc[c], 0, 0, 0);
            acc[c] = __builtin_amdgcn_mfma_f32_16x16x32_bf16(ah, bl, acc[c], 0, 0, 0);
            acc[c] = __builtin_amdgcn_mfma_f32_16x16x32_bf16(al, bh, acc[c], 0, 0, 0);
        }
    }

#pragma unroll
    for (int c = 0; c < 16; c++) {
#pragma unroll
        for (int qq = 0; qq < 4; qq++) {
            size_t row = (size_t)(tbase + r0 + 16 * w + 4 * lq + qq);
            size_t col = 16 * c + lr;
            float v = acc[c][qq];
            if (emitT2) {
                unsigned short h = f2b(v);
                g_t2hi[row * HID + col] = h;
                g_t2lo[row * HID + col] = f2b(v - b2f(h));
            } else {
                g_T[row * HID + col] = v;
            }
        }
    }
}

// ---------------------------------------------------------------------------
// Fused two-stream aggregate; emits h planes + d_out copy.
// ---------------------------------------------------------------------------
__global__ __launch_bounds__(256) void k_agg2(const float* __restrict__ bias,
                                              float* __restrict__ outS,
                                              float* __restrict__ outF) {
    __shared__ float AdjT[NODE][102];
    int tid = threadIdx.x;
    int idx = blockIdx.x;
    int side = idx >> 10;
    int b = (idx & 1023) >> 1;
    int c0 = (idx & 1) * 128;
    const float* Adj = adjPtr(side) + (size_t)b * NODE * NODE;
    const float* Tg = g_T + ((size_t)side * NN + (size_t)b * NODE) * HID;
    float* outp = side ? outF : outS;
    unsigned short* phD = selhi(side);
    unsigned short* plD = sello(side);

    for (int i = tid; i < NODE * NODE; i += 256) {
        int n = i / NODE, k = i - n * NODE;
        AdjT[k][n] = Adj[i];
    }
    for (int i = tid; i < NODE * 12; i += 256) {
        int k = i / 12, n = NODE + (i % 12);
        AdjT[k][n] = 0.f;
    }
    __syncthreads();

    int ti = tid & 15, tj = tid >> 4;
    int rbase = 6 * ti;
    int cc = c0 + 8 * tj;

    float acc[6][8];
#pragma unroll
    for (int i = 0; i < 6; i++)
#pragma unroll
        for (int j = 0; j < 8; j++) acc[i][j] = 0.f;

#pragma unroll 2
    for (int k = 0; k < NODE; k++) {
        float4 t0 = *(const float4*)&Tg[(size_t)k * HID + cc];
        float4 t1 = *(const float4*)&Tg[(size_t)k * HID + cc + 4];
        float bv[8] = {t0.x, t0.y, t0.z, t0.w, t1.x, t1.y, t1.z, t1.w};
        float2 a01 = *(const float2*)&AdjT[k][rbase];
        float2 a23 = *(const float2*)&AdjT[k][rbase + 2];
        float2 a45 = *(const float2*)&AdjT[k][rbase + 4];
        float av[6] = {a01.x, a01.y, a23.x, a23.y, a45.x, a45.y};
#pragma unroll
        for (int i = 0; i < 6; i++)
#pragma unroll
            for (int j = 0; j < 8; j++)
                acc[i][j] = fmaf(av[i], bv[j], acc[i][j]);
    }

    float bb[8];
#pragma unroll
    for (int j = 0; j < 8; j++) bb[j] = bias[cc + j];

#pragma unroll
    for (int i = 0; i < 6; i++) {
        int n = rbase + i;
        if (n < NODE) {
            size_t row = (size_t)(b * NODE + n);
            float v[8];
            unsigned short h8[8], l8[8];
#pragma unroll
            for (int j = 0; j < 8; j++) {
                v[j] = fmaxf(acc[i][j] + bb[j], 0.f);
                unsigned short h = f2b(v[j]);
                h8[j] = h;
                l8[j] = f2b(v[j] - b2f(h));
            }
            *(float4*)&outp[row * 512 + cc] = make_float4(v[0], v[1], v[2], v[3]);
            *(float4*)&outp[row * 512 + cc + 4] = make_float4(v[4], v[5], v[6], v[7]);
            *(uint4*)&phD[row * HID + cc] = *(uint4*)h8;
            *(uint4*)&plD[row * HID + cc] = *(uint4*)l8;
        }
    }
}

// ---------------------------------------------------------------------------
// Fused co-attention per graph (r20-validated): MFMA scores from t2 planes
// (col<92 guard) -> stats -> P in LDS -> PV phases (reg micro-tile, 64-col
// chunks, H reconstructed from hi/lo planes). LDS ~66 KB -> 2 blocks/CU.
// ---------------------------------------------------------------------------
__global__ __launch_bounds__(256) void k_coatt(int hfsel, int hssel,
                                               float* __restrict__ outS,
                                               float* __restrict__ outF,
                                               int cssel, int cfsel, int emit) {
    __shared__ float Pm[96][92];
    __shared__ float rmax_[96], rinv_[96], fn_[96], gm_[96];
    __shared__ unsigned short stage[4][96][ASTR];
    float (*Hl)[68] = reinterpret_cast<float(*)[68]>(&stage[0][0][0]);

    int b = blockIdx.x;
    int tid = threadIdx.x;
    const unsigned short* t2h = g_t2hi + (size_t)b * NODE * HID;
    const unsigned short* t2l = g_t2lo + (size_t)b * NODE * HID;
    const unsigned short* hfh = selhi(hfsel) + (size_t)b * NODE * HID;
    const unsigned short* hfl_ = sello(hfsel) + (size_t)b * NODE * HID;

    // ---- phase A: At = tanh(T2 @ HF^T) via MFMA ----
    {
        int w = tid >> 6, l = tid & 63;
        int lr = l & 15, lq = l >> 4, koff = 8 * lq;
        int wr = w >> 1, wc = w & 1;

        f32x4 acc[3][3];
#pragma unroll
        for (int i = 0; i < 3; i++)
#pragma unroll
            for (int j = 0; j < 3; j++) acc[i][j] = (f32x4){0.f, 0.f, 0.f, 0.f};

        const uint4 z4 = make_uint4(0, 0, 0, 0);
        for (int t = 0; t < 8; t++) {
            int k0 = 32 * t;
            __syncthreads();
            for (int i = tid; i < 96 * 4; i += 256) {
                int r = i >> 2, o = (i & 3) << 3;
                uint4 vah = z4, val = z4, vbh = z4, vbl = z4;
                if (r < NODE) {
                    size_t g = (size_t)r * HID + k0 + o;
                    vah = *(const uint4*)&t2h[g];
                    val = *(const uint4*)&t2l[g];
                    vbh = *(const uint4*)&hfh[g];
                    vbl = *(const uint4*)&hfl_[g];
                }
                *(uint4*)&stage[0][r][o] = vah;
                *(uint4*)&stage[1][r][o] = val;
                *(uint4*)&stage[2][r][o] = vbh;
                *(uint4*)&stage[3][r][o] = vbl;
            }
            __syncthreads();

            bf16x8 ah[3], al[3], bh[3], bl[3];
#pragma unroll
            for (int i = 0; i < 3; i++) {
                ah[i] = *(const bf16x8*)&stage[0][48 * wr + 16 * i + lr][koff];
                al[i] = *(const bf16x8*)&stage[1][48 * wr + 16 * i + lr][koff];
                bh[i] = *(const bf16x8*)&stage[2][48 * wc + 16 * i + lr][koff];
                bl[i] = *(const bf16x8*)&stage[3][48 * wc + 16 * i + lr][koff];
            }
#pragma unroll
            for (int i = 0; i < 3; i++)
#pragma unroll
                for (int j = 0; j < 3; j++) {
                    acc[i][j] = __builtin_amdgcn_mfma_f32_16x16x32_bf16(ah[i], bh[j], acc[i][j], 0, 0, 0);
                    acc[i][j] = __builtin_amdgcn_mfma_f32_16x16x32_bf16(ah[i], bl[j], acc[i][j], 0, 0, 0);
                    acc[i][j] = __builtin_amdgcn_mfma_f32_16x16x32_bf16(al[i], bh[j], acc[i][j], 0, 0, 0);
                }
        }
        __syncthreads();

#pragma unroll
        for (int i = 0; i < 3; i++)
#pragma unroll
            for (int j = 0; j < 3; j++)
#pragma unroll
                for (int qq = 0; qq < 4; qq++) {
                    int row = 48 * wr + 16 * i + 4 * lq + qq;
                    int col = 48 * wc + 16 * j + lr;
                    if (col < 92)
                        Pm[row][col] = tanh_safe(acc[i][j][qq]);
                }
    }
    __syncthreads();

    // ---- softmax stats ----
    if (tid < NODE) {
        int n = tid;
        float mx = -2.f;
        for (int m = 0; m < NODE; m++) mx = fmaxf(mx, Pm[n][m]);
        float s = 0.f;
        for (int m = 0; m < NODE; m++) s += __expf(Pm[n][m] - mx);
        rmax_[n] = mx;
        rinv_[n] = 1.f / s;
        fn_[n] = s * __expf(mx);
    } else if (tid >= 128 && tid < 128 + NODE) {
        int m = tid - 128;
        float mx = -2.f;
        for (int n = 0; n < NODE; n++) mx = fmaxf(mx, Pm[n][m]);
        float s = 0.f;
        for (int n = 0; n < NODE; n++) s += __expf(Pm[n][m] - mx);
        gm_[m] = __expf(-mx) / s;
    }
    __syncthreads();

    // ---- P = row-softmax(At) in place ----
    for (int i = tid; i < NODE * NODE; i += 256) {
        int n = i / NODE, m = i - n * NODE;
        Pm[n][m] = __expf(Pm[n][m] - rmax_[n]) * rinv_[n];
    }

    int tc = (tid & 15) << 2;
    int rg = tid >> 4;
    unsigned short* csh = selhi(cssel);
    unsigned short* csl = sello(cssel);
    unsigned short* cfh = selhi(cfsel);
    unsigned short* cfl = sello(cfsel);

    // ---- phase B: co_s = P @ HF, 4 chunks of 64 cols ----
    for (int c0 = 0; c0 < HID; c0 += 64) {
        __syncthreads();
        for (int i = tid; i < NODE * 8; i += 256) {
            int r = i >> 3, o = (i & 7) << 3;
            uint4 vh = *(const uint4*)&hfh[(size_t)r * HID + c0 + o];
            uint4 vl = *(const uint4*)&hfl_[(size_t)r * HID + c0 + o];
            const unsigned short* ph = (const unsigned short*)&vh;
            const unsigned short* pl = (const unsigned short*)&vl;
#pragma unroll
            for (int j = 0; j < 8; j++)
                Hl[r][o + j] = b2f(ph[j]) + b2f(pl[j]);
        }
        __syncthreads();

        float acc[6][4];
#pragma unroll
        for (int k = 0; k < 6; k++)
#pragma unroll
            for (int j = 0; j < 4; j++) acc[k][j] = 0.f;

#pragma unroll 2
        for (int m = 0; m < NODE; m++) {
            float4 h = *(const float4*)&Hl[m][tc];
#pragma unroll
            for (int k = 0; k < 6; k++) {
                int n = rg + 16 * k;
                float p = Pm[(n < NODE) ? n : 0][m];
                acc[k][0] = fmaf(p, h.x, acc[k][0]);
                acc[k][1] = fmaf(p, h.y, acc[k][1]);
                acc[k][2] = fmaf(p, h.z, acc[k][2]);
                acc[k][3] = fmaf(p, h.w, acc[k][3]);
            }
        }
#pragma unroll
        for (int k = 0; k < 6; k++) {
            int n = rg + 16 * k;
            if (n < NODE) {
                size_t row = (size_t)(b * NODE + n);
                size_t gc = c0 + tc;
                *(float4*)&outS[row * 512 + gc] =
                    make_float4(acc[k][0], acc[k][1], acc[k][2], acc[k][3]);
                if (emit) {
                    unsigned short h4[4], l4[4];
#pragma unroll
                    for (int j = 0; j < 4; j++) {
                        unsigned short h = f2b(acc[k][j]);
                        h4[j] = h;
                        l4[j] = f2b(acc[k][j] - b2f(h));
                    }
                    *(uint2*)&csh[row * HID + gc] = *(uint2*)h4;
                    *(uint2*)&csl[row * HID + gc] = *(uint2*)l4;
                }
            }
        }
    }

    // ---- phase C: co_f[m] = gm[m] * sum_n (P[n][m]*fn[n]) * HS[n] ----
    const unsigned short* hsh = selhi(hssel) + (size_t)b * NODE * HID;
    const unsigned short* hsl = sello(hssel) + (size_t)b * NODE * HID;
    for (int c0 = 0; c0 < HID; c0 += 64) {
        __syncthreads();
        for (int i = tid; i < NODE * 8; i += 256) {
            int r = i >> 3, o = (i & 7) << 3;
            uint4 vh = *(const uint4*)&hsh[(size_t)r * HID + c0 + o];
            uint4 vl = *(const uint4*)&hsl[(size_t)r * HID + c0 + o];
            const unsigned short* ph = (const unsigned short*)&vh;
            const unsigned short* pl = (const unsigned short*)&vl;
#pragma unroll
            for (int j = 0; j < 8; j++)
                Hl[r][o + j] = b2f(ph[j]) + b2f(pl[j]);
        }
        __syncthreads();

        float acc[6][4];
#pragma unroll
        for (int k = 0; k < 6; k++)
#pragma unroll
            for (int j = 0; j < 4; j++) acc[k][j] = 0.f;

#pragma unroll 2
        for (int n = 0; n < NODE; n++) {
            float4 h = *(const float4*)&Hl[n][tc];
            float f = fn_[n];
#pragma unroll
            for (int k = 0; k < 6; k++) {
                int m = rg + 16 * k;
                float p = Pm[n][(m < NODE) ? m : 0] * f;
                acc[k][0] = fmaf(p, h.x, acc[k][0]);
                acc[k][1] = fmaf(p, h.y, acc[k][1]);
                acc[k][2] = fmaf(p, h.z, acc[k][2]);
                acc[k][3] = fmaf(p, h.w, acc[k][3]);
            }
        }
#pragma unroll
        for (int k = 0; k < 6; k++) {
            int m = rg + 16 * k;
            if (m < NODE) {
                float g = gm_[m];
                size_t row = (size_t)(b * NODE + m);
                size_t gc = c0 + tc;
                float o4[4] = {acc[k][0] * g, acc[k][1] * g, acc[k][2] * g, acc[k][3] * g};
                *(float4*)&outF[row * 512 + gc] = make_float4(o4[0], o4[1], o4[2], o4[3]);
                if (emit) {
                    unsigned short h4[4], l4[4];
#pragma unroll
                    for (int j = 0; j < 4; j++) {
                        unsigned short h = f2b(o4[j]);
                        h4[j] = h;
                        l4[j] = f2b(o4[j] - b2f(h));
                    }
                    *(uint2*)&cfh[row * HID + gc] = *(uint2*)h4;
                    *(uint2*)&cfl[row * HID + gc] = *(uint2*)l4;
                }
            }
        }
    }
}

// ---------------------------------------------------------------------------
extern "C" void kernel_launch(void* const* d_in, const int* in_sizes, int n_in,
                              void* d_out, int out_size, void* d_ws, size_t ws_size,
                              hipStream_t stream) {
    const float* x_sc = (const float*)d_in[0];
    const void* e_sc = d_in[1];
    const float* x_fc = (const float*)d_in[2];
    const void* e_fc = d_in[3];
    const float* W0 = (const float*)d_in[4];
    const float* b0 = (const float*)d_in[5];
    const float* W1 = (const float*)d_in[6];
    const float* b1 = (const float*)d_in[7];
    const float* Wa = (const float*)d_in[8];

    float* out = (float*)d_out;
    size_t os = (size_t)NN * 512;
    float* x1s = out;
    float* x2s = out + os;
    float* x1f = out + 2 * os;
    float* x2f = out + 3 * os;

    const int NS = NN / 64;          // 720 row-blocks per side

    k_prep<<<1132, 256, 0, stream>>>(e_sc, e_fc, W0, Wa, W1);

    // ---- layer 1 (fp32 x converted at staging) ----
    k_gemm_mfma<<<2 * NS, 256, 0, stream>>>(6, -1, 6, -1, 90, 96, 0, XLD, 0, NS, x_sc, x_fc);
    k_agg2<<<2048, 256, 0, stream>>>(b0, x1s, x1f);

    // ---- co-attention 1 ----
    k_gemm_mfma<<<NS, 256, 0, stream>>>(0, -1, 0, -1, HID, 256, 1, 256, 1, NS, nullptr, nullptr);
    k_coatt<<<NB, 256, 0, stream>>>(1, 0, x1s + HID, x1f + HID, 2, 3, 1);

    // ---- layer 2 ----
    k_gemm_mfma<<<2 * NS, 256, 0, stream>>>(0, 2, 1, 3, HID, 512, 2, 512, 0, NS, nullptr, nullptr);
    k_agg2<<<2048, 256, 0, stream>>>(b1, x2s, x2f);

    // ---- co-attention 2 ----
    k_gemm_mfma<<<NS, 256, 0, stream>>>(0, -1, 0, -1, HID, 256, 1, 256, 1, NS, nullptr, nullptr);
    k_coatt<<<NB, 256, 0, stream>>>(1, 0, x2s + HID, x2f + HID, 2, 3, 0);
}